// Round 2
// baseline (324.781 us; speedup 1.0000x reference)
//
#include <hip/hip_runtime.h>
#include <math.h>

#define NH 16
#define NKV 4
#define HD 128
#define DIM 2048
#define GQ 4   // NH/NKV
#define EPS 1.1920928955078125e-07f

typedef unsigned short u16;
using bf16x8 = __attribute__((ext_vector_type(8))) short;
using f16x4  = __attribute__((ext_vector_type(4))) _Float16;
using f32x4  = __attribute__((ext_vector_type(4))) float;

__device__ inline float fast_exp2(float x) { return __builtin_amdgcn_exp2f(x); }

__device__ inline short f2bf(float f) {
    unsigned u = __builtin_bit_cast(unsigned, f);
    return (short)((u + 0x7FFFu + ((u >> 16) & 1u)) >> 16);
}
__device__ inline u16 f2h(float f) {
    _Float16 h = (_Float16)f;
    return __builtin_bit_cast(u16, h);
}

#define ASYNC_LOAD16(g, l)                                                        \
    __builtin_amdgcn_global_load_lds(                                             \
        (const __attribute__((address_space(1))) unsigned*)(g),                   \
        (__attribute__((address_space(3))) unsigned*)(l), 16, 0, 0)

#define SCHED_FENCE() __builtin_amdgcn_sched_barrier(0)
#define WAIT_LGKM0()  asm volatile("s_waitcnt lgkmcnt(0)" ::: "memory")
#define WAIT_VM(N)    asm volatile("s_waitcnt vmcnt(" #N ")" ::: "memory")

// ---------------- fp32 -> bf16 convert (vectorized) -------------------------
__global__ __launch_bounds__(256) void cvt_bf16(const float* __restrict__ src,
                                                u16* __restrict__ dst, int n4) {
    int i = blockIdx.x * 256 + threadIdx.x;
    if (i < n4) {
        float4 f = ((const float4*)src)[i];
        ushort4 o;
        o.x = (u16)f2bf(f.x); o.y = (u16)f2bf(f.y);
        o.z = (u16)f2bf(f.z); o.w = (u16)f2bf(f.w);
        ((ushort4*)dst)[i] = o;
    }
}

// ---------------- RoPE cos/sin tables: [T][64] ------------------------------
__global__ __launch_bounds__(64) void rope_tab(float* __restrict__ ct,
                                               float* __restrict__ st,
                                               double base) {
    const int t = blockIdx.x;
    const int j = threadIdx.x;
    const float inv_freq = (float)pow(base, -(double)j / 64.0);
    const float fr = (float)t * inv_freq;
    ct[t * 64 + j] = cosf(fr);
    st[t * 64 + j] = sinf(fr);
}

// ============== 256x256 4-phase pipelined GEMM, counted vmcnt (T4) ==========
// 8 waves (4M x 2N), BK=64, double-buffered 128 KiB LDS, T2 XOR swizzle.
// Staging quantum = one global_load_lds group (64 rows).  Need analysis:
//   P0/P1 read all A-groups + B rows {0-63,128-191} (b0,b2);
//   P2/P3 additionally read b1,b3.
// Issue (for tile kt+1): P0: a0-a3, P1: b0,b2, P2: b1,b3, P3: none.
// Waits: vmcnt(6) at P1-end (retires b1,b3 of CURRENT tile, 3-phase flight),
//        vmcnt(2) at P3-end (retires a*,b0,b2 of NEXT tile; b1,b3 stay in
//        flight across the boundary).  Queue never drains to 0 in the loop.
// LDS layout: row-major [256][64] bf16, 8 chunks of 16B per row,
//   phys_chunk = logical_chunk ^ (row & 7); staged via linear LDS dest +
//   pre-swizzled per-lane global source (both-sides-or-neither).
#define BM 256
#define BN 256
#define BKT 64
#define NKT (DIM / BKT)   // 32

template <int EPI>
__global__ __launch_bounds__(512, 2) void gemm256(
    const u16* __restrict__ A, const u16* __restrict__ W,
    float* __restrict__ C, int N,                       // EPI==0: plain fp32 C
    u16* __restrict__ q16, u16* __restrict__ k16,       // EPI==1: fused QKV
    u16* __restrict__ vt16,
    const float* __restrict__ ctab, const float* __restrict__ stab,
    const float* __restrict__ q_gain, int T) {
    __shared__ u16 As[2][BM * BKT];
    __shared__ u16 Bs[2][BN * BKT];

    const int tid  = threadIdx.x;
    const int wid  = tid >> 6;
    const int lane = tid & 63;
    const int l16  = lane & 15;
    const int quad = lane >> 4;
    const int wm   = wid >> 1;          // 0..3  (64 rows each)
    const int wn   = wid & 1;           // 0..1  (128 cols each = one head)
    const int m0   = blockIdx.x * BM;
    const int n0   = blockIdx.y * BN;
    const int K    = DIM;

    // staging invariants: lane -> (row within 8-row seg, pre-swizzled col)
    const int srow = lane >> 3;                     // 0..7
    const int scol = ((lane & 7) ^ srow) * 8;       // pre-swizzled source col
    const u16* pa = A + (size_t)(m0 + srow) * K + scol;
    const u16* pw = W + (size_t)(n0 + srow) * K + scol;

    // ds_read swizzled chunk offsets: chunk (kk*4+quad) ^ (row&7), row&7==l16&7
    const int ca0 = ((quad)     ^ (l16 & 7)) * 8;   // kk = 0
    const int ca1 = ((4 + quad) ^ (l16 & 7)) * 8;   // kk = 1

    f32x4 acc[4][8];
#pragma unroll
    for (int i = 0; i < 4; i++)
#pragma unroll
        for (int j = 0; j < 8; j++) acc[i][j] = (f32x4){0.f, 0.f, 0.f, 0.f};

    // ---- prologue: stage tile 0 in steady-state age order ----
    //   a0,a1,a2,a3, b0,b2, b1,b3  (oldest first)
#pragma unroll
    for (int r = 0; r < 4; r++)
        ASYNC_LOAD16(pa + (size_t)(r * 64 + wid * 8) * K, &As[0][(r * 64 + wid * 8) * BKT]);
    ASYNC_LOAD16(pw + (size_t)(0 * 64 + wid * 8) * K, &Bs[0][(0 * 64 + wid * 8) * BKT]);
    ASYNC_LOAD16(pw + (size_t)(2 * 64 + wid * 8) * K, &Bs[0][(2 * 64 + wid * 8) * BKT]);
    ASYNC_LOAD16(pw + (size_t)(1 * 64 + wid * 8) * K, &Bs[0][(1 * 64 + wid * 8) * BKT]);
    ASYNC_LOAD16(pw + (size_t)(3 * 64 + wid * 8) * K, &Bs[0][(3 * 64 + wid * 8) * BKT]);
    WAIT_VM(2);                 // a*, b0, b2 landed; b1,b3 may be in flight
    SCHED_FENCE();
    __builtin_amdgcn_s_barrier();
    SCHED_FENCE();

#pragma unroll 1
    for (int kt = 0; kt < NKT; kt++) {
        const int cur = kt & 1;
        const u16* Ac = &As[cur][0];
        const u16* Bc = &Bs[cur][0];
        u16* An = &As[cur ^ 1][0];
        u16* Bn = &Bs[cur ^ 1][0];
        // last tile wraps to k=0: dummy-but-valid loads keep waits uniform
        const size_t ko = (size_t)((kt + 1) & (NKT - 1)) * BKT;

        bf16x8 a0[4], a1[4];

        // -------- P0: A(kk0) x4 + B(nt0-3,kk0) x4; issue a0-a3(next) -------
        {
            bf16x8 bf[4];
#pragma unroll
            for (int mt = 0; mt < 4; mt++)
                a0[mt] = *(const bf16x8*)&Ac[(wm * 64 + mt * 16 + l16) * BKT + ca0];
#pragma unroll
            for (int nt = 0; nt < 4; nt++)
                bf[nt] = *(const bf16x8*)&Bc[(wn * 128 + nt * 16 + l16) * BKT + ca0];
#pragma unroll
            for (int r = 0; r < 4; r++)
                ASYNC_LOAD16(pa + (size_t)(r * 64 + wid * 8) * K + ko,
                             &An[(r * 64 + wid * 8) * BKT]);
            SCHED_FENCE();
            __builtin_amdgcn_s_barrier();
            WAIT_LGKM0();
            SCHED_FENCE();
            __builtin_amdgcn_s_setprio(1);
#pragma unroll
            for (int mt = 0; mt < 4; mt++)
#pragma unroll
                for (int nt = 0; nt < 4; nt++)
                    acc[mt][nt] = __builtin_amdgcn_mfma_f32_16x16x32_bf16(
                        a0[mt], bf[nt], acc[mt][nt], 0, 0, 0);
            __builtin_amdgcn_s_setprio(0);
            SCHED_FENCE();
            __builtin_amdgcn_s_barrier();
        }

        // -------- P1: A(kk1) x4 + B(nt0-3,kk1) x4; issue b0,b2(next) -------
        {
            bf16x8 bf[4];
#pragma unroll
            for (int mt = 0; mt < 4; mt++)
                a1[mt] = *(const bf16x8*)&Ac[(wm * 64 + mt * 16 + l16) * BKT + ca1];
#pragma unroll
            for (int nt = 0; nt < 4; nt++)
                bf[nt] = *(const bf16x8*)&Bc[(wn * 128 + nt * 16 + l16) * BKT + ca1];
            ASYNC_LOAD16(pw + (size_t)(0 * 64 + wid * 8) * K + ko,
                         &Bn[(0 * 64 + wid * 8) * BKT]);
            ASYNC_LOAD16(pw + (size_t)(2 * 64 + wid * 8) * K + ko,
                         &Bn[(2 * 64 + wid * 8) * BKT]);
            SCHED_FENCE();
            __builtin_amdgcn_s_barrier();
            WAIT_LGKM0();
            SCHED_FENCE();
            __builtin_amdgcn_s_setprio(1);
#pragma unroll
            for (int mt = 0; mt < 4; mt++)
#pragma unroll
                for (int nt = 0; nt < 4; nt++)
                    acc[mt][nt] = __builtin_amdgcn_mfma_f32_16x16x32_bf16(
                        a1[mt], bf[nt], acc[mt][nt], 0, 0, 0);
            __builtin_amdgcn_s_setprio(0);
            WAIT_VM(6);   // retire b1,b3 of CURRENT tile (needed by P2 reads)
            SCHED_FENCE();
            __builtin_amdgcn_s_barrier();
            SCHED_FENCE();
        }

        // -------- P2: B(nt4-7,kk0) x4, reuse a0; issue b1,b3(next) ---------
        {
            bf16x8 bf[4];
#pragma unroll
            for (int nt = 0; nt < 4; nt++)
                bf[nt] = *(const bf16x8*)&Bc[(wn * 128 + (nt + 4) * 16 + l16) * BKT + ca0];
            ASYNC_LOAD16(pw + (size_t)(1 * 64 + wid * 8) * K + ko,
                         &Bn[(1 * 64 + wid * 8) * BKT]);
            ASYNC_LOAD16(pw + (size_t)(3 * 64 + wid * 8) * K + ko,
                         &Bn[(3 * 64 + wid * 8) * BKT]);
            SCHED_FENCE();
            __builtin_amdgcn_s_barrier();
            WAIT_LGKM0();
            SCHED_FENCE();
            __builtin_amdgcn_s_setprio(1);
#pragma unroll
            for (int mt = 0; mt < 4; mt++)
#pragma unroll
                for (int nt = 0; nt < 4; nt++)
                    acc[mt][nt + 4] = __builtin_amdgcn_mfma_f32_16x16x32_bf16(
                        a0[mt], bf[nt], acc[mt][nt + 4], 0, 0, 0);
            __builtin_amdgcn_s_setprio(0);
            SCHED_FENCE();
            __builtin_amdgcn_s_barrier();
        }

        // -------- P3: B(nt4-7,kk1) x4, reuse a1; no issue ------------------
        {
            bf16x8 bf[4];
#pragma unroll
            for (int nt = 0; nt < 4; nt++)
                bf[nt] = *(const bf16x8*)&Bc[(wn * 128 + (nt + 4) * 16 + l16) * BKT + ca1];
            SCHED_FENCE();
            __builtin_amdgcn_s_barrier();
            WAIT_LGKM0();
            SCHED_FENCE();
            __builtin_amdgcn_s_setprio(1);
#pragma unroll
            for (int mt = 0; mt < 4; mt++)
#pragma unroll
                for (int nt = 0; nt < 4; nt++)
                    acc[mt][nt + 4] = __builtin_amdgcn_mfma_f32_16x16x32_bf16(
                        a1[mt], bf[nt], acc[mt][nt + 4], 0, 0, 0);
            __builtin_amdgcn_s_setprio(0);
            WAIT_VM(2);   // retire a*,b0,b2 of NEXT tile; b1,b3 stay in flight
            SCHED_FENCE();
            __builtin_amdgcn_s_barrier();
            SCHED_FENCE();
        }
    }
    WAIT_VM(0);   // drain wrap-around dummy loads before epilogue/endpgm

    // --------------------------- epilogues ---------------------------------
    if constexpr (EPI == 0) {
#pragma unroll
        for (int mt = 0; mt < 4; mt++)
#pragma unroll
            for (int nt = 0; nt < 8; nt++)
#pragma unroll
                for (int r = 0; r < 4; r++)
                    C[(size_t)(m0 + wm * 64 + mt * 16 + quad * 4 + r) * N +
                      n0 + wn * 128 + nt * 16 + l16] = acc[mt][nt][r];
    } else {
        const int nb = n0 + wn * 128;           // head-aligned column base
        if (nb < 2560) {                        // ---- Q or K: RMSNorm + RoPE
            const bool isQ = (nb < 2048);
            const float gval =
                isQ ? (q_gain[nb >> 7] * 0.08838834764831843f * 1.4426950408889634f)
                    : 1.0f;
#pragma unroll
            for (int mt = 0; mt < 4; mt++) {
#pragma unroll
                for (int r = 0; r < 4; r++) {
                    float s = 0.f;
#pragma unroll
                    for (int nt = 0; nt < 8; nt++) {
                        float a = acc[mt][nt][r];
                        s = fmaf(a, a, s);
                    }
                    s += __shfl_xor(s, 1);
                    s += __shfl_xor(s, 2);
                    s += __shfl_xor(s, 4);
                    s += __shfl_xor(s, 8);
                    const float scale = rsqrtf(s * (1.0f / HD) + EPS) * gval;
                    const int m = m0 + wm * 64 + mt * 16 + quad * 4 + r;
                    const int t = m & (T - 1);
                    const float* ct = ctab + t * 64;
                    const float* st = stab + t * 64;
                    u16* dst = isQ ? (q16 + (size_t)m * 2048 + nb)
                                   : (k16 + (size_t)m * 512 + (nb - 2048));
#pragma unroll
                    for (int nt = 0; nt < 4; nt++) {
                        const int j = nt * 16 + l16;
                        const float c = ct[j], sn = st[j];
                        const float x1 = acc[mt][nt][r] * scale;
                        const float x2 = acc[mt][nt + 4][r] * scale;
                        dst[j]      = (u16)f2bf(x1 * c + x2 * sn);
                        dst[j + 64] = (u16)f2bf(x2 * c - x1 * sn);
                    }
                }
            }
        } else {                                // ---- V: f16, transposed [d][t]
#pragma unroll
            for (int mt = 0; mt < 4; mt++) {
                const int mb = m0 + wm * 64 + mt * 16 + quad * 4;
                const int b = mb >> 11;          // T == 2048
                const int t0 = mb & (T - 1);
#pragma unroll
                for (int nt = 0; nt < 8; nt++) {
                    const int dcol = nb - 2560 + nt * 16 + l16;
                    const int kvh = dcol >> 7;
                    const int d = dcol & (HD - 1);
                    ushort4 o;
                    o.x = f2h(acc[mt][nt][0]);
                    o.y = f2h(acc[mt][nt][1]);
                    o.z = f2h(acc[mt][nt][2]);
                    o.w = f2h(acc[mt][nt][3]);
                    *(ushort4*)(vt16 + ((size_t)((b * NKV + kvh) * HD + d)) * T + t0) = o;
                }
            }
        }
    }
}

// ------ flash attention v4: DMA-staged double buffer, XOR-swizzled LDS ------
// S^T = K Q^T (bf16 x32); softmax in registers (exp2); O^T = V^T P^T (f16 x16)
#define QT 64
#define SK 64

__global__ __launch_bounds__(256) void flash4(const u16* __restrict__ q16,
                                              const u16* __restrict__ k16,
                                              const u16* __restrict__ vt16,
                                              u16* __restrict__ y16, int T) {
    __shared__ u16 Ks[2][SK * 128];
    __shared__ u16 Vt[2][HD * 64];

    const int tid = threadIdx.x;
    const int wave = tid >> 6;
    const int lane = tid & 63;
    const int l16 = lane & 15;
    const int quad = lane >> 4;

    const int bid = blockIdx.x;
    const int bh = bid & 31;          // b*NH + h
    const int pr = bid >> 5;          // pair index 0..T/QT/2-1
    const int h = bh & 15;
    const int b = bh >> 4;
    const int kv = h / GQ;

    const u16* kg = k16 + ((size_t)b * T * NKV + kv) * HD;
    const u16* vg = vt16 + (size_t)(b * NKV + kv) * HD * T;

    const int krow_in_seg = lane >> 4;          // 0..3
    const int kclog_base = lane & 15;           // phys chunk; logical = phys ^ (r&15)
    const int vrow_in_seg = lane >> 3;          // 0..7
    const int vclog = (lane & 7) ^ (lane >> 3); // logical chunk

#pragma unroll 1
    for (int half = 0; half < 2; half++) {
        const int qt = half ? (T / QT - 1 - pr) : pr;
        const int q0 = qt * QT;
        const int qglob = q0 + wave * 16 + l16;
        const int nts = q0 / SK + 1;

        bf16x8 qf[4];
        {
            const u16* qp = q16 + ((size_t)(b * T + qglob) * NH + h) * HD;
#pragma unroll
            for (int kc = 0; kc < 4; kc++)
                qf[kc] = *(const bf16x8*)(qp + kc * 32 + quad * 8);
        }

        f32x4 of[8];
#pragma unroll
        for (int i = 0; i < 8; i++) of[i] = (f32x4){0.f, 0.f, 0.f, 0.f};
        float m_i = -1e30f, l_i = 0.0f;

        __syncthreads();
#pragma unroll
        for (int j = 0; j < 4; j++) {
            const int seg = wave * 4 + j;
            const int r = seg * 4 + krow_in_seg;
            const int clog = kclog_base ^ (r & 15);
            ASYNC_LOAD16(kg + (size_t)r * (NKV * HD) + clog * 8, &Ks[0][seg * 512]);
            const int d = seg * 8 + vrow_in_seg;
            ASYNC_LOAD16(vg + (size_t)d * T + vclog * 8, &Vt[0][seg * 512]);
        }

        for (int it = 0; it < nts; it++) {
            const int cur = it & 1;
            __syncthreads();

            if (it + 1 < nts) {
                const int s1 = (it + 1) * SK;
#pragma unroll
                for (int j = 0; j < 4; j++) {
                    const int seg = wave * 4 + j;
                    const int r = seg * 4 + krow_in_seg;
                    const int clog = kclog_base ^ (r & 15);
                    ASYNC_LOAD16(kg + (size_t)(s1 + r) * (NKV * HD) + clog * 8,
                                 &Ks[cur ^ 1][seg * 512]);
                    const int d = seg * 8 + vrow_in_seg;
                    ASYNC_LOAD16(vg + (size_t)d * T + s1 + vclog * 8,
                                 &Vt[cur ^ 1][seg * 512]);
                }
            }

            f32x4 sf[4];
#pragma unroll
            for (int st = 0; st < 4; st++) sf[st] = (f32x4){0.f, 0.f, 0.f, 0.f};
#pragma unroll
            for (int kc = 0; kc < 4; kc++)
#pragma unroll
                for (int st = 0; st < 4; st++) {
                    const int row = st * 16 + l16;
                    bf16x8 kf = *(const bf16x8*)
                        &Ks[cur][row * 128 + (((kc * 4 + quad) ^ l16) * 8)];
                    sf[st] = __builtin_amdgcn_mfma_f32_16x16x32_bf16(kf, qf[kc], sf[st], 0, 0, 0);
                }

            if (it == nts - 1) {
#pragma unroll
                for (int st = 0; st < 4; st++)
#pragma unroll
                    for (int r = 0; r < 4; r++)
                        if (q0 + st * 16 + quad * 4 + r > qglob) sf[st][r] = -1e30f;
            }

            float tm = -1e30f;
#pragma unroll
            for (int st = 0; st < 4; st++)
#pragma unroll
                for (int r = 0; r < 4; r++) tm = fmaxf(tm, sf[st][r]);
            tm = fmaxf(tm, __shfl_xor(tm, 16));
            tm = fmaxf(tm, __shfl_xor(tm, 32));

            const float mprev = m_i;
            const float mnew = fmaxf(mprev, tm);
            m_i = mnew;
            const float alpha = fast_exp2(mprev - mnew);

            f16x4 pf[4];
            float ls = 0.0f;
#pragma unroll
            for (int st = 0; st < 4; st++)
#pragma unroll
                for (int r = 0; r < 4; r++) {
                    float e = fast_exp2(sf[st][r] - mnew);
                    ls += e;
                    pf[st][r] = (_Float16)e;
                }
            ls += __shfl_xor(ls, 16);
            ls += __shfl_xor(ls, 32);
            l_i = alpha * l_i + ls;

            if (__ballot(mnew > mprev)) {
#pragma unroll
                for (int dt = 0; dt < 8; dt++)
#pragma unroll
                    for (int r = 0; r < 4; r++) of[dt][r] *= alpha;
            }

#pragma unroll
            for (int st = 0; st < 4; st++) {
                const int clog = st * 2 + (quad >> 1);
#pragma unroll
                for (int dt = 0; dt < 8; dt++) {
                    const int d = dt * 16 + l16;
                    const int phys = clog ^ (l16 & 7);
                    f16x4 va = *(const f16x4*)
                        &Vt[cur][d * 64 + phys * 8 + (quad & 1) * 4];
                    of[dt] = __builtin_amdgcn_mfma_f32_16x16x16f16(va, pf[st], of[dt], 0, 0, 0);
                }
            }
        }

        const float inv = 1.0f / l_i;
        u16* yp = y16 + ((size_t)(b * T + qglob) * NH + h) * HD + quad * 4;
#pragma unroll
        for (int dt = 0; dt < 8; dt++) {
            ushort4 o;
            o.x = (u16)f2bf(of[dt][0] * inv);
            o.y = (u16)f2bf(of[dt][1] * inv);
            o.z = (u16)f2bf(of[dt][2] * inv);
            o.w = (u16)f2bf(of[dt][3] * inv);
            *(ushort4*)(yp + dt * 16) = o;
        }
    }
}

// ---------------------------------------------------------------------------
extern "C" void kernel_launch(void* const* d_in, const int* in_sizes, int n_in,
                              void* d_out, int out_size, void* d_ws, size_t ws_size,
                              hipStream_t stream) {
    const float* x      = (const float*)d_in[0];
    const float* Wq     = (const float*)d_in[1];
    const float* Wk     = (const float*)d_in[2];
    const float* Wv     = (const float*)d_in[3];
    const float* Wp     = (const float*)d_in[4];
    const float* q_gain = (const float*)d_in[5];
    float* out = (float*)d_out;

    const int B = 2;
    const int BT = in_sizes[0] / DIM;      // 4096
    const int T = BT / B;                  // 2048
    const int KD = NKV * HD;               // 512

    u16* x16   = (u16*)d_ws;                        // BT*DIM        (later y16)
    u16* wqkv  = x16 + (size_t)BT * DIM;            // 3072*DIM
    u16* wp16  = wqkv + (size_t)3072 * DIM;         // DIM*DIM
    u16* q16   = wp16 + (size_t)DIM * DIM;          // BT*DIM
    u16* k16   = q16 + (size_t)BT * DIM;            // BT*KD
    u16* vt16  = k16 + (size_t)BT * KD;             // BT*KD
    float* ctab = (float*)(vt16 + (size_t)BT * KD); // T*64
    float* stab = ctab + (size_t)T * 64;            // T*64
    u16* y16   = x16;

    double base = 10000.0;
    if (T > 1024) base = 10000.0 * pow((double)T / 1024.0, 128.0 / 126.0);

    const int nx4  = BT * DIM / 4;
    const int nwq4 = DIM * DIM / 4;
    const int nwk4 = KD * DIM / 4;

    cvt_bf16<<<(nx4 + 255) / 256, 256, 0, stream>>>(x, x16, nx4);
    cvt_bf16<<<(nwq4 + 255) / 256, 256, 0, stream>>>(Wq, wqkv, nwq4);
    cvt_bf16<<<(nwk4 + 255) / 256, 256, 0, stream>>>(Wk, wqkv + (size_t)2048 * DIM, nwk4);
    cvt_bf16<<<(nwk4 + 255) / 256, 256, 0, stream>>>(Wv, wqkv + (size_t)2560 * DIM, nwk4);
    cvt_bf16<<<(nwq4 + 255) / 256, 256, 0, stream>>>(Wp, wp16, nwq4);
    rope_tab<<<T, 64, 0, stream>>>(ctab, stab, base);

    gemm256<1><<<dim3(BT / BM, 3072 / BN), 512, 0, stream>>>(
        x16, wqkv, nullptr, 0, q16, k16, vt16, ctab, stab, q_gain, T);

    flash4<<<32 * (T / QT / 2), 256, 0, stream>>>(q16, k16, vt16, y16, T);

    gemm256<0><<<dim3(BT / BM, DIM / 128 / 2), 512, 0, stream>>>(
        y16, wp16, out, DIM, nullptr, nullptr, nullptr, nullptr, nullptr, nullptr, T);
}

// Round 3
// 304.021 us; speedup vs baseline: 1.0683x; 1.0683x over previous
//
#include <hip/hip_runtime.h>
#include <math.h>

#define NH 16
#define NKV 4
#define HD 128
#define DIM 2048
#define GQ 4   // NH/NKV
#define EPS 1.1920928955078125e-07f

typedef unsigned short u16;
using bf16x8 = __attribute__((ext_vector_type(8))) short;
using f16x4  = __attribute__((ext_vector_type(4))) _Float16;
using f32x4  = __attribute__((ext_vector_type(4))) float;

__device__ inline float fast_exp2(float x) { return __builtin_amdgcn_exp2f(x); }

__device__ inline short f2bf(float f) {
    unsigned u = __builtin_bit_cast(unsigned, f);
    return (short)((u + 0x7FFFu + ((u >> 16) & 1u)) >> 16);
}
__device__ inline u16 f2h(float f) {
    _Float16 h = (_Float16)f;
    return __builtin_bit_cast(u16, h);
}

#define ASYNC_LOAD16(g, l)                                                        \
    __builtin_amdgcn_global_load_lds(                                             \
        (const __attribute__((address_space(1))) unsigned*)(g),                   \
        (__attribute__((address_space(3))) unsigned*)(l), 16, 0, 0)

#define SCHED_FENCE() __builtin_amdgcn_sched_barrier(0)
#define WAIT_LGKM0()  asm volatile("s_waitcnt lgkmcnt(0)" ::: "memory")
#define WAIT_VM(N)    asm volatile("s_waitcnt vmcnt(" #N ")" ::: "memory")

// ---------------- fused fp32 -> bf16 convert (all 5 tensors) ----------------
__global__ __launch_bounds__(256) void cvt_fused(
    const float* __restrict__ x,  const float* __restrict__ wq,
    const float* __restrict__ wk, const float* __restrict__ wv,
    const float* __restrict__ wp,
    u16* __restrict__ x16, u16* __restrict__ wqkv, u16* __restrict__ wp16,
    int nx4, int total) {
    int i = blockIdx.x * 256 + threadIdx.x;
    if (i >= total) return;
    const int nw4 = DIM * DIM / 4;          // 1048576
    const int nk4 = (NKV * HD) * DIM / 4;   // 262144
    const float4* s4;
    ushort4* d4;
    if (i < nx4) {
        s4 = (const float4*)x + i; d4 = (ushort4*)x16 + i;
    } else {
        int j = i - nx4;
        if (j < nw4) {
            s4 = (const float4*)wq + j; d4 = (ushort4*)wqkv + j;
        } else {
            j -= nw4;
            if (j < nk4) {
                s4 = (const float4*)wk + j;
                d4 = (ushort4*)wqkv + (size_t)2048 * DIM / 4 + j;
            } else {
                j -= nk4;
                if (j < nk4) {
                    s4 = (const float4*)wv + j;
                    d4 = (ushort4*)wqkv + (size_t)2560 * DIM / 4 + j;
                } else {
                    j -= nk4;
                    s4 = (const float4*)wp + j; d4 = (ushort4*)wp16 + j;
                }
            }
        }
    }
    float4 f = *s4;
    ushort4 o;
    o.x = (u16)f2bf(f.x); o.y = (u16)f2bf(f.y);
    o.z = (u16)f2bf(f.z); o.w = (u16)f2bf(f.w);
    *d4 = o;
}

// ---------------- RoPE cos/sin tables: [T][64], float-only ------------------
__global__ __launch_bounds__(256) void rope_tab(float* __restrict__ ct,
                                                float* __restrict__ st,
                                                float l2b64) {
    const int idx = blockIdx.x * 256 + threadIdx.x;
    const int t = idx >> 6;
    const int j = idx & 63;
    const float inv_freq = fast_exp2(-(float)j * l2b64);
    const float fr = (float)t * inv_freq;
    ct[idx] = cosf(fr);
    st[idx] = sinf(fr);
}

// ============ BMx256 4-phase pipelined GEMM, counted vmcnt (T4) =============
// 8 waves (4M x 2N), BK=64, double-buffered LDS, T2 XOR swizzle.
// MT = number of 64-row A groups (BM = MT*64).  Per-wave rows = MT*16.
// Issue (for tile kt+1): P0: a0..a(MT-1), P1: b0,b2, P2: b1,b3, P3: none.
// Waits: vmcnt(MT+2) at P1-end (retires b1,b3 of CURRENT tile),
//        vmcnt(2) at P3-end (retires a*,b0,b2 of NEXT tile).
// Queue never drains to 0 in the loop.
#define BN 256
#define BKT 64
#define NKT (DIM / BKT)   // 32

template <int EPI, int MT>
__global__ __launch_bounds__(512, 2) void gemm256(
    const u16* __restrict__ A, const u16* __restrict__ W,
    float* __restrict__ C, int N,                       // EPI==0: plain fp32 C
    u16* __restrict__ q16, u16* __restrict__ k16,       // EPI==1: fused QKV
    u16* __restrict__ vt16,
    const float* __restrict__ ctab, const float* __restrict__ stab,
    const float* __restrict__ q_gain, int T) {
    __shared__ u16 As[2][MT * 64 * BKT];
    __shared__ u16 Bs[2][BN * BKT];

    const int tid  = threadIdx.x;
    const int wid  = tid >> 6;
    const int lane = tid & 63;
    const int l16  = lane & 15;
    const int quad = lane >> 4;
    const int wm   = wid >> 1;          // 0..3  (MT*16 rows each)
    const int wn   = wid & 1;           // 0..1  (128 cols each)
    const int m0   = blockIdx.x * (MT * 64);
    const int n0   = blockIdx.y * BN;
    const int K    = DIM;

    // staging invariants: lane -> (row within 8-row seg, pre-swizzled col)
    const int srow = lane >> 3;                     // 0..7
    const int scol = ((lane & 7) ^ srow) * 8;       // pre-swizzled source col
    const u16* pa = A + (size_t)(m0 + srow) * K + scol;
    const u16* pw = W + (size_t)(n0 + srow) * K + scol;

    // ds_read swizzled chunk offsets
    const int ca0 = ((quad)     ^ (l16 & 7)) * 8;   // kk = 0
    const int ca1 = ((4 + quad) ^ (l16 & 7)) * 8;   // kk = 1

    f32x4 acc[MT][8];
#pragma unroll
    for (int i = 0; i < MT; i++)
#pragma unroll
        for (int j = 0; j < 8; j++) acc[i][j] = (f32x4){0.f, 0.f, 0.f, 0.f};

    // ---- prologue: stage tile 0 in steady-state age order ----
#pragma unroll
    for (int r = 0; r < MT; r++)
        ASYNC_LOAD16(pa + (size_t)(r * 64 + wid * 8) * K, &As[0][(r * 64 + wid * 8) * BKT]);
    ASYNC_LOAD16(pw + (size_t)(0 * 64 + wid * 8) * K, &Bs[0][(0 * 64 + wid * 8) * BKT]);
    ASYNC_LOAD16(pw + (size_t)(2 * 64 + wid * 8) * K, &Bs[0][(2 * 64 + wid * 8) * BKT]);
    ASYNC_LOAD16(pw + (size_t)(1 * 64 + wid * 8) * K, &Bs[0][(1 * 64 + wid * 8) * BKT]);
    ASYNC_LOAD16(pw + (size_t)(3 * 64 + wid * 8) * K, &Bs[0][(3 * 64 + wid * 8) * BKT]);
    WAIT_VM(2);                 // a*, b0, b2 landed; b1,b3 may be in flight
    SCHED_FENCE();
    __builtin_amdgcn_s_barrier();
    SCHED_FENCE();

#pragma unroll 1
    for (int kt = 0; kt < NKT; kt++) {
        const int cur = kt & 1;
        const u16* Ac = &As[cur][0];
        const u16* Bc = &Bs[cur][0];
        u16* An = &As[cur ^ 1][0];
        u16* Bn = &Bs[cur ^ 1][0];
        // last tile wraps to k=0: dummy-but-valid loads keep waits uniform
        const size_t ko = (size_t)((kt + 1) & (NKT - 1)) * BKT;

        bf16x8 a0[MT], a1[MT];

        // -------- P0: A(kk0) + B(nt0-3,kk0); issue a*(next) ----------------
        {
            bf16x8 bf[4];
#pragma unroll
            for (int mt = 0; mt < MT; mt++)
                a0[mt] = *(const bf16x8*)&Ac[(wm * (MT * 16) + mt * 16 + l16) * BKT + ca0];
#pragma unroll
            for (int nt = 0; nt < 4; nt++)
                bf[nt] = *(const bf16x8*)&Bc[(wn * 128 + nt * 16 + l16) * BKT + ca0];
#pragma unroll
            for (int r = 0; r < MT; r++)
                ASYNC_LOAD16(pa + (size_t)(r * 64 + wid * 8) * K + ko,
                             &An[(r * 64 + wid * 8) * BKT]);
            SCHED_FENCE();
            __builtin_amdgcn_s_barrier();
            WAIT_LGKM0();
            SCHED_FENCE();
            __builtin_amdgcn_s_setprio(1);
#pragma unroll
            for (int mt = 0; mt < MT; mt++)
#pragma unroll
                for (int nt = 0; nt < 4; nt++)
                    acc[mt][nt] = __builtin_amdgcn_mfma_f32_16x16x32_bf16(
                        a0[mt], bf[nt], acc[mt][nt], 0, 0, 0);
            __builtin_amdgcn_s_setprio(0);
            SCHED_FENCE();
            __builtin_amdgcn_s_barrier();
        }

        // -------- P1: A(kk1) + B(nt0-3,kk1); issue b0,b2(next) -------------
        {
            bf16x8 bf[4];
#pragma unroll
            for (int mt = 0; mt < MT; mt++)
                a1[mt] = *(const bf16x8*)&Ac[(wm * (MT * 16) + mt * 16 + l16) * BKT + ca1];
#pragma unroll
            for (int nt = 0; nt < 4; nt++)
                bf[nt] = *(const bf16x8*)&Bc[(wn * 128 + nt * 16 + l16) * BKT + ca1];
            ASYNC_LOAD16(pw + (size_t)(0 * 64 + wid * 8) * K + ko,
                         &Bn[(0 * 64 + wid * 8) * BKT]);
            ASYNC_LOAD16(pw + (size_t)(2 * 64 + wid * 8) * K + ko,
                         &Bn[(2 * 64 + wid * 8) * BKT]);
            SCHED_FENCE();
            __builtin_amdgcn_s_barrier();
            WAIT_LGKM0();
            SCHED_FENCE();
            __builtin_amdgcn_s_setprio(1);
#pragma unroll
            for (int mt = 0; mt < MT; mt++)
#pragma unroll
                for (int nt = 0; nt < 4; nt++)
                    acc[mt][nt] = __builtin_amdgcn_mfma_f32_16x16x32_bf16(
                        a1[mt], bf[nt], acc[mt][nt], 0, 0, 0);
            __builtin_amdgcn_s_setprio(0);
            if constexpr (MT == 4) { WAIT_VM(6); } else { WAIT_VM(4); }
            SCHED_FENCE();
            __builtin_amdgcn_s_barrier();
            SCHED_FENCE();
        }

        // -------- P2: B(nt4-7,kk0), reuse a0; issue b1,b3(next) ------------
        {
            bf16x8 bf[4];
#pragma unroll
            for (int nt = 0; nt < 4; nt++)
                bf[nt] = *(const bf16x8*)&Bc[(wn * 128 + (nt + 4) * 16 + l16) * BKT + ca0];
            ASYNC_LOAD16(pw + (size_t)(1 * 64 + wid * 8) * K + ko,
                         &Bn[(1 * 64 + wid * 8) * BKT]);
            ASYNC_LOAD16(pw + (size_t)(3 * 64 + wid * 8) * K + ko,
                         &Bn[(3 * 64 + wid * 8) * BKT]);
            SCHED_FENCE();
            __builtin_amdgcn_s_barrier();
            WAIT_LGKM0();
            SCHED_FENCE();
            __builtin_amdgcn_s_setprio(1);
#pragma unroll
            for (int mt = 0; mt < MT; mt++)
#pragma unroll
                for (int nt = 0; nt < 4; nt++)
                    acc[mt][nt + 4] = __builtin_amdgcn_mfma_f32_16x16x32_bf16(
                        a0[mt], bf[nt], acc[mt][nt + 4], 0, 0, 0);
            __builtin_amdgcn_s_setprio(0);
            SCHED_FENCE();
            __builtin_amdgcn_s_barrier();
        }

        // -------- P3: B(nt4-7,kk1), reuse a1; no issue ---------------------
        {
            bf16x8 bf[4];
#pragma unroll
            for (int nt = 0; nt < 4; nt++)
                bf[nt] = *(const bf16x8*)&Bc[(wn * 128 + (nt + 4) * 16 + l16) * BKT + ca1];
            SCHED_FENCE();
            __builtin_amdgcn_s_barrier();
            WAIT_LGKM0();
            SCHED_FENCE();
            __builtin_amdgcn_s_setprio(1);
#pragma unroll
            for (int mt = 0; mt < MT; mt++)
#pragma unroll
                for (int nt = 0; nt < 4; nt++)
                    acc[mt][nt + 4] = __builtin_amdgcn_mfma_f32_16x16x32_bf16(
                        a1[mt], bf[nt], acc[mt][nt + 4], 0, 0, 0);
            __builtin_amdgcn_s_setprio(0);
            WAIT_VM(2);   // retire a*,b0,b2 of NEXT tile; b1,b3 stay in flight
            SCHED_FENCE();
            __builtin_amdgcn_s_barrier();
            SCHED_FENCE();
        }
    }
    WAIT_VM(0);   // drain wrap-around dummy loads before epilogue/endpgm

    // --------------------------- epilogues ---------------------------------
    if constexpr (EPI == 0) {
#pragma unroll
        for (int mt = 0; mt < MT; mt++)
#pragma unroll
            for (int nt = 0; nt < 8; nt++)
#pragma unroll
                for (int r = 0; r < 4; r++)
                    C[(size_t)(m0 + wm * (MT * 16) + mt * 16 + quad * 4 + r) * N +
                      n0 + wn * 128 + nt * 16 + l16] = acc[mt][nt][r];
    } else {
        const int nb = n0 + wn * 128;           // head-aligned column base
        if (nb < 2560) {                        // ---- Q or K: RMSNorm + RoPE
            const bool isQ = (nb < 2048);
            const float gval =
                isQ ? (q_gain[nb >> 7] * 0.08838834764831843f * 1.4426950408889634f)
                    : 1.0f;
#pragma unroll
            for (int mt = 0; mt < MT; mt++) {
#pragma unroll
                for (int r = 0; r < 4; r++) {
                    float s = 0.f;
#pragma unroll
                    for (int nt = 0; nt < 8; nt++) {
                        float a = acc[mt][nt][r];
                        s = fmaf(a, a, s);
                    }
                    s += __shfl_xor(s, 1);
                    s += __shfl_xor(s, 2);
                    s += __shfl_xor(s, 4);
                    s += __shfl_xor(s, 8);
                    const float scale = rsqrtf(s * (1.0f / HD) + EPS) * gval;
                    const int m = m0 + wm * (MT * 16) + mt * 16 + quad * 4 + r;
                    const int t = m & (T - 1);
                    const float* ct = ctab + t * 64;
                    const float* st = stab + t * 64;
                    u16* dst = isQ ? (q16 + (size_t)m * 2048 + nb)
                                   : (k16 + (size_t)m * 512 + (nb - 2048));
#pragma unroll
                    for (int nt = 0; nt < 4; nt++) {
                        const int j = nt * 16 + l16;
                        const float c = ct[j], sn = st[j];
                        const float x1 = acc[mt][nt][r] * scale;
                        const float x2 = acc[mt][nt + 4][r] * scale;
                        dst[j]      = (u16)f2bf(x1 * c + x2 * sn);
                        dst[j + 64] = (u16)f2bf(x2 * c - x1 * sn);
                    }
                }
            }
        } else {                                // ---- V: f16, transposed [d][t]
#pragma unroll
            for (int mt = 0; mt < MT; mt++) {
                const int mb = m0 + wm * (MT * 16) + mt * 16 + quad * 4;
                const int b = mb >> 11;          // T == 2048
                const int t0 = mb & (T - 1);
#pragma unroll
                for (int nt = 0; nt < 8; nt++) {
                    const int dcol = nb - 2560 + nt * 16 + l16;
                    const int kvh = dcol >> 7;
                    const int d = dcol & (HD - 1);
                    ushort4 o;
                    o.x = f2h(acc[mt][nt][0]);
                    o.y = f2h(acc[mt][nt][1]);
                    o.z = f2h(acc[mt][nt][2]);
                    o.w = f2h(acc[mt][nt][3]);
                    *(ushort4*)(vt16 + ((size_t)((b * NKV + kvh) * HD + d)) * T + t0) = o;
                }
            }
        }
    }
}

// ------ flash attention v5: 8 waves, QT=128, 4 waves/SIMD co-residency ------
// S^T = K Q^T (bf16 x32); softmax in registers (exp2, defer-max THR=8);
// O^T = V^T P^T (f16 x16).  Same XOR-swizzled K/V LDS layout as v4.
// Grid: 32 bh x 16 qt (no pairing).  qt mapping: block i and i+256 land on
// the same CU (round-robin) and get qt and 15-qt -> constant work per CU.
#define QT 128
#define SK 64

__global__ __launch_bounds__(512) void flash5(const u16* __restrict__ q16,
                                              const u16* __restrict__ k16,
                                              const u16* __restrict__ vt16,
                                              u16* __restrict__ y16, int T) {
    __shared__ u16 Ks[2][SK * 128];
    __shared__ u16 Vt[2][HD * 64];

    const int tid = threadIdx.x;
    const int wave = tid >> 6;        // 0..7
    const int lane = tid & 63;
    const int l16 = lane & 15;
    const int quad = lane >> 4;

    const int bid = blockIdx.x;
    const int bh = bid & 31;          // b*NH + h
    const int qi = bid >> 5;          // 0..nqt-1
    const int nqt = T / QT;           // 16
    const int qt = (qi < (nqt >> 1)) ? qi : (nqt - 1 - (qi - (nqt >> 1)));
    const int h = bh & 15;
    const int b = bh >> 4;
    const int kv = h / GQ;

    const u16* kg = k16 + ((size_t)b * T * NKV + kv) * HD;
    const u16* vg = vt16 + (size_t)(b * NKV + kv) * HD * T;

    const int krow_in_seg = lane >> 4;          // 0..3
    const int kclog_base = lane & 15;           // phys chunk; logical = phys ^ (r&15)
    const int vrow_in_seg = lane >> 3;          // 0..7
    const int vclog = (lane & 7) ^ (lane >> 3); // logical chunk

    const int q0 = qt * QT;
    const int qglob = q0 + wave * 16 + l16;
    const int nts = q0 / SK + 2;      // two diagonal-ish tiles

    bf16x8 qf[4];
    {
        const u16* qp = q16 + ((size_t)(b * T + qglob) * NH + h) * HD;
#pragma unroll
        for (int kc = 0; kc < 4; kc++)
            qf[kc] = *(const bf16x8*)(qp + kc * 32 + quad * 8);
    }

    f32x4 of[8];
#pragma unroll
    for (int i = 0; i < 8; i++) of[i] = (f32x4){0.f, 0.f, 0.f, 0.f};
    float m_i = -1e30f, l_i = 0.0f;

    // preload tile 0: 16 K segs + 16 V segs, 2+2 per wave
#pragma unroll
    for (int j = 0; j < 2; j++) {
        const int seg = wave * 2 + j;
        const int r = seg * 4 + krow_in_seg;
        const int clog = kclog_base ^ (r & 15);
        ASYNC_LOAD16(kg + (size_t)r * (NKV * HD) + clog * 8, &Ks[0][seg * 512]);
        const int d = seg * 8 + vrow_in_seg;
        ASYNC_LOAD16(vg + (size_t)d * T + vclog * 8, &Vt[0][seg * 512]);
    }

    for (int it = 0; it < nts; it++) {
        const int cur = it & 1;
        __syncthreads();   // drains DMA for tile `it` (one full phase in flight)

        if (it + 1 < nts) {
            const int s1 = (it + 1) * SK;
#pragma unroll
            for (int j = 0; j < 2; j++) {
                const int seg = wave * 2 + j;
                const int r = seg * 4 + krow_in_seg;
                const int clog = kclog_base ^ (r & 15);
                ASYNC_LOAD16(kg + (size_t)(s1 + r) * (NKV * HD) + clog * 8,
                             &Ks[cur ^ 1][seg * 512]);
                const int d = seg * 8 + vrow_in_seg;
                ASYNC_LOAD16(vg + (size_t)d * T + s1 + vclog * 8,
                             &Vt[cur ^ 1][seg * 512]);
            }
        }

        // waves 0-3 are fully masked on the last diagonal tile: skip compute
        if (it == nts - 1 && wave < 4) continue;

        // S^T = K Q^T
        f32x4 sf[4];
#pragma unroll
        for (int st = 0; st < 4; st++) sf[st] = (f32x4){0.f, 0.f, 0.f, 0.f};
#pragma unroll
        for (int kc = 0; kc < 4; kc++)
#pragma unroll
            for (int st = 0; st < 4; st++) {
                const int row = st * 16 + l16;
                bf16x8 kf = *(const bf16x8*)
                    &Ks[cur][row * 128 + (((kc * 4 + quad) ^ l16) * 8)];
                sf[st] = __builtin_amdgcn_mfma_f32_16x16x32_bf16(kf, qf[kc], sf[st], 0, 0, 0);
            }

        if (it >= nts - 2) {  // diagonal tiles: causal mask
            const int s0 = it * SK;
#pragma unroll
            for (int st = 0; st < 4; st++)
#pragma unroll
                for (int r = 0; r < 4; r++)
                    if (s0 + st * 16 + quad * 4 + r > qglob) sf[st][r] = -1e30f;
        }

        float tm = -1e30f;
#pragma unroll
        for (int st = 0; st < 4; st++)
#pragma unroll
            for (int r = 0; r < 4; r++) tm = fmaxf(tm, sf[st][r]);
        tm = fmaxf(tm, __shfl_xor(tm, 16));
        tm = fmaxf(tm, __shfl_xor(tm, 32));

        // defer-max (T13): only rescale when max grew by > 8 (log2 units)
        if (__ballot(tm > m_i + 8.0f)) {
            const float mnew = fmaxf(m_i, tm);
            const float alpha = fast_exp2(m_i - mnew);
            m_i = mnew;
            l_i *= alpha;
#pragma unroll
            for (int dt = 0; dt < 8; dt++)
#pragma unroll
                for (int r = 0; r < 4; r++) of[dt][r] *= alpha;
        }

        f16x4 pf[4];
        float ls = 0.0f;
#pragma unroll
        for (int st = 0; st < 4; st++)
#pragma unroll
            for (int r = 0; r < 4; r++) {
                float e = fast_exp2(sf[st][r] - m_i);
                ls += e;
                pf[st][r] = (_Float16)e;
            }
        ls += __shfl_xor(ls, 16);
        ls += __shfl_xor(ls, 32);
        l_i += ls;

        // O^T += V^T P^T
#pragma unroll
        for (int st = 0; st < 4; st++) {
            const int clog = st * 2 + (quad >> 1);
#pragma unroll
            for (int dt = 0; dt < 8; dt++) {
                const int d = dt * 16 + l16;
                const int phys = clog ^ (l16 & 7);
                f16x4 va = *(const f16x4*)
                    &Vt[cur][d * 64 + phys * 8 + (quad & 1) * 4];
                of[dt] = __builtin_amdgcn_mfma_f32_16x16x16f16(va, pf[st], of[dt], 0, 0, 0);
            }
        }
    }

    const float inv = 1.0f / l_i;
    u16* yp = y16 + ((size_t)(b * T + qglob) * NH + h) * HD + quad * 4;
#pragma unroll
    for (int dt = 0; dt < 8; dt++) {
        ushort4 o;
        o.x = (u16)f2bf(of[dt][0] * inv);
        o.y = (u16)f2bf(of[dt][1] * inv);
        o.z = (u16)f2bf(of[dt][2] * inv);
        o.w = (u16)f2bf(of[dt][3] * inv);
        *(ushort4*)(yp + dt * 16) = o;
    }
}

// ---------------------------------------------------------------------------
extern "C" void kernel_launch(void* const* d_in, const int* in_sizes, int n_in,
                              void* d_out, int out_size, void* d_ws, size_t ws_size,
                              hipStream_t stream) {
    const float* x      = (const float*)d_in[0];
    const float* Wq     = (const float*)d_in[1];
    const float* Wk     = (const float*)d_in[2];
    const float* Wv     = (const float*)d_in[3];
    const float* Wp     = (const float*)d_in[4];
    const float* q_gain = (const float*)d_in[5];
    float* out = (float*)d_out;

    const int B = 2;
    const int BT = in_sizes[0] / DIM;      // 4096
    const int T = BT / B;                  // 2048
    const int KD = NKV * HD;               // 512

    u16* x16   = (u16*)d_ws;                        // BT*DIM        (later y16)
    u16* wqkv  = x16 + (size_t)BT * DIM;            // 3072*DIM
    u16* wp16  = wqkv + (size_t)3072 * DIM;         // DIM*DIM
    u16* q16   = wp16 + (size_t)DIM * DIM;          // BT*DIM
    u16* k16   = q16 + (size_t)BT * DIM;            // BT*KD
    u16* vt16  = k16 + (size_t)BT * KD;             // BT*KD
    float* ctab = (float*)(vt16 + (size_t)BT * KD); // T*64
    float* stab = ctab + (size_t)T * 64;            // T*64
    u16* y16   = x16;

    double base = 10000.0;
    if (T > 1024) base = 10000.0 * pow((double)T / 1024.0, 128.0 / 126.0);
    const float l2b64 = (float)(log2(base) / 64.0);

    const int nx4  = BT * DIM / 4;
    const int total4 = nx4 + 2 * (DIM * DIM / 4) + 2 * (KD * DIM / 4);

    cvt_fused<<<(total4 + 255) / 256, 256, 0, stream>>>(
        x, Wq, Wk, Wv, Wp, x16, wqkv, wp16, nx4, total4);
    rope_tab<<<(T * 64 + 255) / 256, 256, 0, stream>>>(ctab, stab, l2b64);

    gemm256<1, 4><<<dim3(BT / 256, 3072 / BN), 512, 0, stream>>>(
        x16, wqkv, nullptr, 0, q16, k16, vt16, ctab, stab, q_gain, T);

    flash5<<<32 * (T / QT), 512, 0, stream>>>(q16, k16, vt16, y16, T);

    gemm256<0, 2><<<dim3(BT / 128, DIM / BN), 512, 0, stream>>>(
        y16, wp16, out, DIM, nullptr, nullptr, nullptr, nullptr, nullptr, nullptr, T);
}